// Round 3
// baseline (323.803 us; speedup 1.0000x reference)
//
#include <hip/hip_runtime.h>
#include <hip/hip_bf16.h>

typedef __attribute__((ext_vector_type(8))) short          s16x8;
typedef __attribute__((ext_vector_type(8))) unsigned short u16x8;
typedef __attribute__((ext_vector_type(4))) float          f4;

__device__ __forceinline__ float bf2f(unsigned short u) {
    union { unsigned int i; float f; } x; x.i = ((unsigned int)u) << 16; return x.f;
}
__device__ __forceinline__ unsigned short f2bf(float f) {
    __hip_bfloat16 h = __float2bfloat16(f);
    return *reinterpret_cast<unsigned short*>(&h);
}
__device__ __forceinline__ void gload_lds16(const void* g, void* l) {
    __builtin_amdgcn_global_load_lds(
        (const __attribute__((address_space(1))) unsigned int*)g,
        (__attribute__((address_space(3))) unsigned int*)l, 16, 0, 0);
}

// Convert the 4 weight matrices (each 512x512 fp32) to bf16, concatenated.
__global__ __launch_bounds__(256) void cvt_w4(const float* __restrict__ a,
                                              const float* __restrict__ b,
                                              const float* __restrict__ c,
                                              const float* __restrict__ d,
                                              unsigned short* __restrict__ o) {
    const int i   = (blockIdx.x * 256 + threadIdx.x) * 8;  // 4*262144 elems
    const int seg = i >> 18;
    const int off = i & 262143;
    const float* s = (seg == 0) ? a : (seg == 1) ? b : (seg == 2) ? c : d;
    f4 x0 = *(const f4*)(s + off);
    f4 x1 = *(const f4*)(s + off + 4);
    unsigned short t[8];
    t[0] = f2bf(x0[0]); t[1] = f2bf(x0[1]); t[2] = f2bf(x0[2]); t[3] = f2bf(x0[3]);
    t[4] = f2bf(x1[0]); t[5] = f2bf(x1[1]); t[6] = f2bf(x1[2]); t[7] = f2bf(x1[3]);
    *(u16x8*)(o + i) = *(u16x8*)t;
}

// OUT[m][n] = (sum_k A[m][k] * W[n][k] + bias[n]) * scale
// m97 structure: global_load_lds width-16 staging, BK=64, 2-barrier loop.
// A fp32 staged as fp32 (cvt at frag-read); W pre-converted bf16.
template <bool AF32, bool OF32>
__global__ __launch_bounds__(256) void gemm97(const void* __restrict__ Ap,
                                              const unsigned short* __restrict__ Wb,
                                              const float* __restrict__ bias,
                                              void* __restrict__ Outp,
                                              float scale) {
    constexpr int KD = 512, BK = 64;
    constexpr int ABYTES = AF32 ? 128 * BK * 4 : 128 * BK * 2;
    __shared__ unsigned char lds[ABYTES + 128 * BK * 2];
    float*          AsF = (float*)lds;
    unsigned short* AsB = (unsigned short*)lds;
    unsigned short* Bs  = (unsigned short*)(lds + ABYTES);

    const int tid  = threadIdx.x;
    const int lane = tid & 63;
    const int w    = tid >> 6;        // wave id 0..3
    const int wm   = w >> 1;
    const int wn   = w & 1;
    const int n0   = blockIdx.x * 128;
    const size_t m0 = (size_t)blockIdx.y * 128;

    const float*          Af = (const float*)Ap;
    const unsigned short* Ab = (const unsigned short*)Ap;

    const int fr = lane & 15;         // frag row (A) / col (B/D)
    const int ko = (lane >> 4) * 8;   // frag k-offset (elements)

    f4 acc[4][4];
#pragma unroll
    for (int i = 0; i < 4; ++i)
#pragma unroll
        for (int j = 0; j < 4; ++j) acc[i][j] = (f4)(0.0f);

    auto stage = [&](int kt) {
        if constexpr (AF32) {
            // A fp32 tile 128x64 (32 KB): wave w covers rows [w*32, w*32+32)
            const int r  = w * 32 + (lane >> 4);   // + i*4
            const int cc = (lane & 15) * 4;
#pragma unroll
            for (int i = 0; i < 8; ++i)
                gload_lds16(Af + (m0 + r + i * 4) * KD + kt + cc,
                            lds + w * 8192 + i * 1024);
        } else {
            // A bf16 tile 128x64 (16 KB)
            const int r  = w * 32 + (lane >> 3);   // + i*8
            const int cc = (lane & 7) * 8;
#pragma unroll
            for (int i = 0; i < 4; ++i)
                gload_lds16(Ab + (m0 + r + i * 8) * KD + kt + cc,
                            lds + w * 4096 + i * 1024);
        }
        {
            // W bf16 tile 128x64 (16 KB)
            const int r  = w * 32 + (lane >> 3);
            const int cc = (lane & 7) * 8;
#pragma unroll
            for (int i = 0; i < 4; ++i)
                gload_lds16(Wb + (size_t)(n0 + r + i * 8) * KD + kt + cc,
                            (unsigned char*)Bs + w * 4096 + i * 1024);
        }
    };

    stage(0);
    for (int t = 0; t < KD / BK; ++t) {
        __syncthreads();   // drains vmcnt: staged tile ready
#pragma unroll
        for (int kk = 0; kk < 2; ++kk) {
            s16x8 af[4], bf[4];
#pragma unroll
            for (int mi = 0; mi < 4; ++mi) {
                const int row = wm * 64 + mi * 16 + fr;
                if constexpr (AF32) {
                    const float* p = AsF + row * BK + kk * 32 + ko;
                    f4 x0 = *(const f4*)p;
                    f4 x1 = *(const f4*)(p + 4);
                    unsigned short u[8];
                    u[0] = f2bf(x0[0]); u[1] = f2bf(x0[1]);
                    u[2] = f2bf(x0[2]); u[3] = f2bf(x0[3]);
                    u[4] = f2bf(x1[0]); u[5] = f2bf(x1[1]);
                    u[6] = f2bf(x1[2]); u[7] = f2bf(x1[3]);
                    af[mi] = *(s16x8*)u;
                } else {
                    af[mi] = *(const s16x8*)(AsB + row * BK + kk * 32 + ko);
                }
            }
#pragma unroll
            for (int ni = 0; ni < 4; ++ni) {
                const int row = wn * 64 + ni * 16 + fr;
                bf[ni] = *(const s16x8*)(Bs + row * BK + kk * 32 + ko);
            }
#pragma unroll
            for (int mi = 0; mi < 4; ++mi)
#pragma unroll
                for (int ni = 0; ni < 4; ++ni)
                    acc[mi][ni] = __builtin_amdgcn_mfma_f32_16x16x32_bf16(
                        af[mi], bf[ni], acc[mi][ni], 0, 0, 0);
        }
        __syncthreads();   // all waves done reading LDS
        if (t + 1 < KD / BK) stage((t + 1) * BK);
    }

    const int rq = (lane >> 4) << 2;
#pragma unroll
    for (int ni = 0; ni < 4; ++ni) {
        const int   col = n0 + wn * 64 + ni * 16 + fr;
        const float bv  = bias[col];
#pragma unroll
        for (int mi = 0; mi < 4; ++mi) {
            const size_t rbase = m0 + wm * 64 + mi * 16 + rq;
#pragma unroll
            for (int r = 0; r < 4; ++r) {
                const float val = (acc[mi][ni][r] + bv) * scale;
                if constexpr (OF32)
                    ((float*)Outp)[(rbase + r) * KD + col] = val;
                else
                    ((unsigned short*)Outp)[(rbase + r) * KD + col] = f2bf(val);
            }
        }
    }
}

// LDS-tiled NAT: one block per (b, head, 16x16 pixel tile).
__global__ __launch_bounds__(256) void natt(const unsigned short* __restrict__ qh,
                                            const unsigned short* __restrict__ kh,
                                            const unsigned short* __restrict__ vh,
                                            const float* __restrict__ rpb,
                                            unsigned short* __restrict__ xout) {
    constexpr int LDK = 40;
    __shared__ unsigned short KV[484][LDK];
    __shared__ float Rs[169];

    const int tid = threadIdx.x;
    const int h   = blockIdx.z & 15;
    const int b   = blockIdx.z >> 4;
    const int x0  = blockIdx.x * 16;
    const int y0  = blockIdx.y * 16;
    const int ux0 = min(max(x0 - 3, 0), 106);
    const int uy0 = min(max(y0 - 3, 0), 106);
    const int tx  = tid & 15;
    const int ty  = tid >> 4;
    const int x   = x0 + tx;
    const int y   = y0 + ty;

    if (tid < 169) Rs[tid] = rpb[h * 169 + tid];

    const long imgbase = (long)b * 128 * 128;

#pragma unroll 2
    for (int kk = tid; kk < 484; kk += 256) {
        const int ky = uy0 + kk / 22;
        const int kx = ux0 + kk % 22;
        const unsigned short* src = kh + (imgbase + ky * 128 + kx) * 512 + h * 32;
#pragma unroll
        for (int j = 0; j < 4; ++j)
            *(u16x8*)&KV[kk][j * 8] = *(const u16x8*)(src + j * 8);
    }

    const long pix = imgbase + y * 128 + x;
    const unsigned short* qp = qh + pix * 512 + h * 32;
    float qv[32];
#pragma unroll
    for (int j = 0; j < 4; ++j) {
        u16x8 v = *(const u16x8*)(qp + j * 8);
#pragma unroll
        for (int e = 0; e < 8; ++e) qv[j * 8 + e] = bf2f(v[e]);
    }

    const int myy = min(max(y - 3, 0), 121) - uy0;
    const int myx = min(max(x - 3, 0), 121) - ux0;
    const int pbY = (y < 3) ? (6 - y) : ((y >= 125) ? (127 - y) : 3);
    const int pbX = (x < 3) ? (6 - x) : ((x >= 125) ? (127 - x) : 3);

    __syncthreads();

    float logit[49];
#pragma unroll
    for (int a = 0; a < 7; ++a) {
        const int rowk = (myy + a) * 22 + myx;
#pragma unroll
        for (int c = 0; c < 7; ++c) {
            const unsigned short* kp = &KV[rowk + c][0];
            float s = 0.f;
#pragma unroll
            for (int j = 0; j < 4; ++j) {
                u16x8 v = *(const u16x8*)(kp + j * 8);
#pragma unroll
                for (int e = 0; e < 8; ++e) s = fmaf(qv[j * 8 + e], bf2f(v[e]), s);
            }
            logit[a * 7 + c] = s + Rs[(pbY + a) * 13 + pbX + c];
        }
    }

    float m = logit[0];
#pragma unroll
    for (int i = 1; i < 49; ++i) m = fmaxf(m, logit[i]);
    float sum = 0.f;
#pragma unroll
    for (int i = 0; i < 49; ++i) {
        float p = exp2f((logit[i] - m) * 1.4426950408889634f);
        logit[i] = p;
        sum += p;
    }
    const float rinv = 1.f / sum;
#pragma unroll
    for (int i = 0; i < 49; ++i) logit[i] *= rinv;

    __syncthreads();

#pragma unroll 2
    for (int kk = tid; kk < 484; kk += 256) {
        const int ky = uy0 + kk / 22;
        const int kx = ux0 + kk % 22;
        const unsigned short* src = vh + (imgbase + ky * 128 + kx) * 512 + h * 32;
#pragma unroll
        for (int j = 0; j < 4; ++j)
            *(u16x8*)&KV[kk][j * 8] = *(const u16x8*)(src + j * 8);
    }
    __syncthreads();

    float acc[32];
#pragma unroll
    for (int d = 0; d < 32; ++d) acc[d] = 0.f;
#pragma unroll
    for (int a = 0; a < 7; ++a) {
        const int rowk = (myy + a) * 22 + myx;
#pragma unroll
        for (int c = 0; c < 7; ++c) {
            const unsigned short* vp = &KV[rowk + c][0];
            const float wgt = logit[a * 7 + c];
#pragma unroll
            for (int j = 0; j < 4; ++j) {
                u16x8 v = *(const u16x8*)(vp + j * 8);
#pragma unroll
                for (int e = 0; e < 8; ++e)
                    acc[j * 8 + e] = fmaf(wgt, bf2f(v[e]), acc[j * 8 + e]);
            }
        }
    }

    unsigned short* op = xout + pix * 512 + h * 32;
#pragma unroll
    for (int j = 0; j < 4; ++j) {
        unsigned short t[8];
#pragma unroll
        for (int e = 0; e < 8; ++e) t[e] = f2bf(acc[j * 8 + e]);
        *(u16x8*)(op + j * 8) = *(u16x8*)t;
    }
}

extern "C" void kernel_launch(void* const* d_in, const int* in_sizes, int n_in,
                              void* d_out, int out_size, void* d_ws, size_t ws_size,
                              hipStream_t stream) {
    const float* q   = (const float*)d_in[0];
    const float* k   = (const float*)d_in[1];
    const float* v   = (const float*)d_in[2];
    const float* wq  = (const float*)d_in[3];
    const float* bq  = (const float*)d_in[4];
    const float* wk  = (const float*)d_in[5];
    const float* bk  = (const float*)d_in[6];
    const float* wv  = (const float*)d_in[7];
    const float* bv  = (const float*)d_in[8];
    const float* rpb = (const float*)d_in[9];
    const float* wo  = (const float*)d_in[10];
    const float* bo  = (const float*)d_in[11];

    const long P = 2l * 128 * 128;  // 32768 pixels
    unsigned short* qh = (unsigned short*)d_ws;
    unsigned short* kh = qh + P * 512;
    unsigned short* vh = kh + P * 512;
    unsigned short* xb = vh + P * 512;
    unsigned short* Wb = xb + P * 512;   // 4 x 512 x 512 bf16 (2 MB)

    const float scale = 0.17677669529663687f;  // 32^-0.5
    const dim3 gg(4, 256, 1);                  // N/128 x M/128

    cvt_w4<<<512, 256, 0, stream>>>(wq, wk, wv, wo, Wb);

    gemm97<true, false><<<gg, 256, 0, stream>>>(q, Wb,          bq, qh, scale);
    gemm97<true, false><<<gg, 256, 0, stream>>>(k, Wb + 262144, bk, kh, 1.0f);
    gemm97<true, false><<<gg, 256, 0, stream>>>(v, Wb + 524288, bv, vh, 1.0f);

    natt<<<dim3(8, 8, 32), 256, 0, stream>>>(qh, kh, vh, rpb, xb);

    gemm97<false, true><<<gg, 256, 0, stream>>>(xb, Wb + 786432, bo, (float*)d_out, 1.0f);
}

// Round 4
// 309.490 us; speedup vs baseline: 1.0462x; 1.0462x over previous
//
#include <hip/hip_runtime.h>
#include <hip/hip_bf16.h>

typedef __attribute__((ext_vector_type(8))) short          s16x8;
typedef __attribute__((ext_vector_type(8))) unsigned short u16x8;
typedef __attribute__((ext_vector_type(4))) float          f4;

__device__ __forceinline__ float bf2f(unsigned short u) {
    union { unsigned int i; float f; } x; x.i = ((unsigned int)u) << 16; return x.f;
}
__device__ __forceinline__ unsigned short f2bf(float f) {
    __hip_bfloat16 h = __float2bfloat16(f);
    return *reinterpret_cast<unsigned short*>(&h);
}
__device__ __forceinline__ void gload_lds16(const void* g, void* l) {
    __builtin_amdgcn_global_load_lds(
        (const __attribute__((address_space(1))) unsigned int*)g,
        (__attribute__((address_space(3))) unsigned int*)l, 16, 0, 0);
}

// Convert the 4 weight matrices (each 512x512 fp32) to bf16, concatenated.
__global__ __launch_bounds__(256) void cvt_w4(const float* __restrict__ a,
                                              const float* __restrict__ b,
                                              const float* __restrict__ c,
                                              const float* __restrict__ d,
                                              unsigned short* __restrict__ o) {
    const int i   = (blockIdx.x * 256 + threadIdx.x) * 8;  // 4*262144 elems
    const int seg = i >> 18;
    const int off = i & 262143;
    const float* s = (seg == 0) ? a : (seg == 1) ? b : (seg == 2) ? c : d;
    f4 x0 = *(const f4*)(s + off);
    f4 x1 = *(const f4*)(s + off + 4);
    unsigned short t[8];
    t[0] = f2bf(x0[0]); t[1] = f2bf(x0[1]); t[2] = f2bf(x0[2]); t[3] = f2bf(x0[3]);
    t[4] = f2bf(x1[0]); t[5] = f2bf(x1[1]); t[6] = f2bf(x1[2]); t[7] = f2bf(x1[3]);
    *(u16x8*)(o + i) = *(u16x8*)t;
}

// OUT[m][n] = (sum_k A[m][k] * W[n][k] + bias[n]) * scale
// m97 staging + XCD-chunked block swizzle: the 4 N-tile blocks that share an
// A-panel land on the SAME XCD so the panel is fetched from HBM once and
// served 3x from that XCD's L2 (round-robin hw mapping: wg i -> XCD i%8).
template <bool AF32, bool OF32>
__global__ __launch_bounds__(256) void gemm97(const void* __restrict__ Ap,
                                              const unsigned short* __restrict__ Wb,
                                              const float* __restrict__ bias,
                                              void* __restrict__ Outp,
                                              float scale) {
    constexpr int KD = 512, BK = 64;
    constexpr int ABYTES = AF32 ? 128 * BK * 4 : 128 * BK * 2;
    __shared__ unsigned char lds[ABYTES + 128 * BK * 2];
    float*          AsF = (float*)lds;
    unsigned short* AsB = (unsigned short*)lds;
    unsigned short* Bs  = (unsigned short*)(lds + ABYTES);

    // bijective chunked XCD swizzle: grid 1024 = 256 m-tiles x 4 n-tiles
    const int swz = (blockIdx.x & 7) * 128 + (blockIdx.x >> 3);
    const int mt  = swz >> 2;
    const int nt  = swz & 3;

    const int tid  = threadIdx.x;
    const int lane = tid & 63;
    const int w    = tid >> 6;        // wave id 0..3
    const int wm   = w >> 1;
    const int wn   = w & 1;
    const int n0   = nt * 128;
    const size_t m0 = (size_t)mt * 128;

    const float*          Af = (const float*)Ap;
    const unsigned short* Ab = (const unsigned short*)Ap;

    const int fr = lane & 15;         // frag row (A) / col (B/D)
    const int ko = (lane >> 4) * 8;   // frag k-offset (elements)

    f4 acc[4][4];
#pragma unroll
    for (int i = 0; i < 4; ++i)
#pragma unroll
        for (int j = 0; j < 4; ++j) acc[i][j] = (f4)(0.0f);

    auto stage = [&](int kt) {
        if constexpr (AF32) {
            // A fp32 tile 128x64 (32 KB): wave w covers rows [w*32, w*32+32)
            const int r  = w * 32 + (lane >> 4);   // + i*4
            const int cc = (lane & 15) * 4;
#pragma unroll
            for (int i = 0; i < 8; ++i)
                gload_lds16(Af + (m0 + r + i * 4) * KD + kt + cc,
                            lds + w * 8192 + i * 1024);
        } else {
            // A bf16 tile 128x64 (16 KB)
            const int r  = w * 32 + (lane >> 3);   // + i*8
            const int cc = (lane & 7) * 8;
#pragma unroll
            for (int i = 0; i < 4; ++i)
                gload_lds16(Ab + (m0 + r + i * 8) * KD + kt + cc,
                            lds + w * 4096 + i * 1024);
        }
        {
            // W bf16 tile 128x64 (16 KB)
            const int r  = w * 32 + (lane >> 3);
            const int cc = (lane & 7) * 8;
#pragma unroll
            for (int i = 0; i < 4; ++i)
                gload_lds16(Wb + (size_t)(n0 + r + i * 8) * KD + kt + cc,
                            (unsigned char*)Bs + w * 4096 + i * 1024);
        }
    };

    stage(0);
    for (int t = 0; t < KD / BK; ++t) {
        __syncthreads();   // drains vmcnt: staged tile ready
#pragma unroll
        for (int kk = 0; kk < 2; ++kk) {
            s16x8 af[4], bf[4];
#pragma unroll
            for (int mi = 0; mi < 4; ++mi) {
                const int row = wm * 64 + mi * 16 + fr;
                if constexpr (AF32) {
                    const float* p = AsF + row * BK + kk * 32 + ko;
                    f4 x0 = *(const f4*)p;
                    f4 x1 = *(const f4*)(p + 4);
                    unsigned short u[8];
                    u[0] = f2bf(x0[0]); u[1] = f2bf(x0[1]);
                    u[2] = f2bf(x0[2]); u[3] = f2bf(x0[3]);
                    u[4] = f2bf(x1[0]); u[5] = f2bf(x1[1]);
                    u[6] = f2bf(x1[2]); u[7] = f2bf(x1[3]);
                    af[mi] = *(s16x8*)u;
                } else {
                    af[mi] = *(const s16x8*)(AsB + row * BK + kk * 32 + ko);
                }
            }
#pragma unroll
            for (int ni = 0; ni < 4; ++ni) {
                const int row = wn * 64 + ni * 16 + fr;
                bf[ni] = *(const s16x8*)(Bs + row * BK + kk * 32 + ko);
            }
#pragma unroll
            for (int mi = 0; mi < 4; ++mi)
#pragma unroll
                for (int ni = 0; ni < 4; ++ni)
                    acc[mi][ni] = __builtin_amdgcn_mfma_f32_16x16x32_bf16(
                        af[mi], bf[ni], acc[mi][ni], 0, 0, 0);
        }
        __syncthreads();   // all waves done reading LDS
        if (t + 1 < KD / BK) stage((t + 1) * BK);
    }

    const int rq = (lane >> 4) << 2;
#pragma unroll
    for (int ni = 0; ni < 4; ++ni) {
        const int   col = n0 + wn * 64 + ni * 16 + fr;
        const float bv  = bias[col];
#pragma unroll
        for (int mi = 0; mi < 4; ++mi) {
            const size_t rbase = m0 + wm * 64 + mi * 16 + rq;
#pragma unroll
            for (int r = 0; r < 4; ++r) {
                const float val = (acc[mi][ni][r] + bv) * scale;
                if constexpr (OF32)
                    ((float*)Outp)[(rbase + r) * KD + col] = val;
                else
                    ((unsigned short*)Outp)[(rbase + r) * KD + col] = f2bf(val);
            }
        }
    }
}

// LDS-tiled NAT: one block per (b, head, 16x16 pixel tile).
__global__ __launch_bounds__(256) void natt(const unsigned short* __restrict__ qh,
                                            const unsigned short* __restrict__ kh,
                                            const unsigned short* __restrict__ vh,
                                            const float* __restrict__ rpb,
                                            unsigned short* __restrict__ xout) {
    constexpr int LDK = 40;
    __shared__ unsigned short KV[484][LDK];
    __shared__ float Rs[169];

    const int tid = threadIdx.x;
    const int h   = blockIdx.z & 15;
    const int b   = blockIdx.z >> 4;
    const int x0  = blockIdx.x * 16;
    const int y0  = blockIdx.y * 16;
    const int ux0 = min(max(x0 - 3, 0), 106);
    const int uy0 = min(max(y0 - 3, 0), 106);
    const int tx  = tid & 15;
    const int ty  = tid >> 4;
    const int x   = x0 + tx;
    const int y   = y0 + ty;

    if (tid < 169) Rs[tid] = rpb[h * 169 + tid];

    const long imgbase = (long)b * 128 * 128;

#pragma unroll 2
    for (int kk = tid; kk < 484; kk += 256) {
        const int ky = uy0 + kk / 22;
        const int kx = ux0 + kk % 22;
        const unsigned short* src = kh + (imgbase + ky * 128 + kx) * 512 + h * 32;
#pragma unroll
        for (int j = 0; j < 4; ++j)
            *(u16x8*)&KV[kk][j * 8] = *(const u16x8*)(src + j * 8);
    }

    const long pix = imgbase + y * 128 + x;
    const unsigned short* qp = qh + pix * 512 + h * 32;
    float qv[32];
#pragma unroll
    for (int j = 0; j < 4; ++j) {
        u16x8 v = *(const u16x8*)(qp + j * 8);
#pragma unroll
        for (int e = 0; e < 8; ++e) qv[j * 8 + e] = bf2f(v[e]);
    }

    const int myy = min(max(y - 3, 0), 121) - uy0;
    const int myx = min(max(x - 3, 0), 121) - ux0;
    const int pbY = (y < 3) ? (6 - y) : ((y >= 125) ? (127 - y) : 3);
    const int pbX = (x < 3) ? (6 - x) : ((x >= 125) ? (127 - x) : 3);

    __syncthreads();

    float logit[49];
#pragma unroll
    for (int a = 0; a < 7; ++a) {
        const int rowk = (myy + a) * 22 + myx;
#pragma unroll
        for (int c = 0; c < 7; ++c) {
            const unsigned short* kp = &KV[rowk + c][0];
            float s = 0.f;
#pragma unroll
            for (int j = 0; j < 4; ++j) {
                u16x8 v = *(const u16x8*)(kp + j * 8);
#pragma unroll
                for (int e = 0; e < 8; ++e) s = fmaf(qv[j * 8 + e], bf2f(v[e]), s);
            }
            logit[a * 7 + c] = s + Rs[(pbY + a) * 13 + pbX + c];
        }
    }

    float m = logit[0];
#pragma unroll
    for (int i = 1; i < 49; ++i) m = fmaxf(m, logit[i]);
    float sum = 0.f;
#pragma unroll
    for (int i = 0; i < 49; ++i) {
        float p = exp2f((logit[i] - m) * 1.4426950408889634f);
        logit[i] = p;
        sum += p;
    }
    const float rinv = 1.f / sum;
#pragma unroll
    for (int i = 0; i < 49; ++i) logit[i] *= rinv;

    __syncthreads();

#pragma unroll 2
    for (int kk = tid; kk < 484; kk += 256) {
        const int ky = uy0 + kk / 22;
        const int kx = ux0 + kk % 22;
        const unsigned short* src = vh + (imgbase + ky * 128 + kx) * 512 + h * 32;
#pragma unroll
        for (int j = 0; j < 4; ++j)
            *(u16x8*)&KV[kk][j * 8] = *(const u16x8*)(src + j * 8);
    }
    __syncthreads();

    float acc[32];
#pragma unroll
    for (int d = 0; d < 32; ++d) acc[d] = 0.f;
#pragma unroll
    for (int a = 0; a < 7; ++a) {
        const int rowk = (myy + a) * 22 + myx;
#pragma unroll
        for (int c = 0; c < 7; ++c) {
            const unsigned short* vp = &KV[rowk + c][0];
            const float wgt = logit[a * 7 + c];
#pragma unroll
            for (int j = 0; j < 4; ++j) {
                u16x8 v = *(const u16x8*)(vp + j * 8);
#pragma unroll
                for (int e = 0; e < 8; ++e)
                    acc[j * 8 + e] = fmaf(wgt, bf2f(v[e]), acc[j * 8 + e]);
            }
        }
    }

    unsigned short* op = xout + pix * 512 + h * 32;
#pragma unroll
    for (int j = 0; j < 4; ++j) {
        unsigned short t[8];
#pragma unroll
        for (int e = 0; e < 8; ++e) t[e] = f2bf(acc[j * 8 + e]);
        *(u16x8*)(op + j * 8) = *(u16x8*)t;
    }
}

extern "C" void kernel_launch(void* const* d_in, const int* in_sizes, int n_in,
                              void* d_out, int out_size, void* d_ws, size_t ws_size,
                              hipStream_t stream) {
    const float* q   = (const float*)d_in[0];
    const float* k   = (const float*)d_in[1];
    const float* v   = (const float*)d_in[2];
    const float* wq  = (const float*)d_in[3];
    const float* bq  = (const float*)d_in[4];
    const float* wk  = (const float*)d_in[5];
    const float* bk  = (const float*)d_in[6];
    const float* wv  = (const float*)d_in[7];
    const float* bv  = (const float*)d_in[8];
    const float* rpb = (const float*)d_in[9];
    const float* wo  = (const float*)d_in[10];
    const float* bo  = (const float*)d_in[11];

    const long P = 2l * 128 * 128;  // 32768 pixels
    unsigned short* qh = (unsigned short*)d_ws;
    unsigned short* kh = qh + P * 512;
    unsigned short* vh = kh + P * 512;
    unsigned short* xb = vh + P * 512;
    unsigned short* Wb = xb + P * 512;   // 4 x 512 x 512 bf16 (2 MB)

    const float scale = 0.17677669529663687f;  // 32^-0.5

    cvt_w4<<<512, 256, 0, stream>>>(wq, wk, wv, wo, Wb);

    gemm97<true, false><<<1024, 256, 0, stream>>>(q, Wb,          bq, qh, scale);
    gemm97<true, false><<<1024, 256, 0, stream>>>(k, Wb + 262144, bk, kh, 1.0f);
    gemm97<true, false><<<1024, 256, 0, stream>>>(v, Wb + 524288, bv, vh, 1.0f);

    natt<<<dim3(8, 8, 32), 256, 0, stream>>>(qh, kh, vh, rpb, xb);

    gemm97<false, true><<<1024, 256, 0, stream>>>(xb, Wb + 786432, bo, (float*)d_out, 1.0f);
}

// Round 6
// 264.449 us; speedup vs baseline: 1.2244x; 1.1703x over previous
//
#include <hip/hip_runtime.h>
#include <hip/hip_bf16.h>

typedef __attribute__((ext_vector_type(8))) short          s16x8;
typedef __attribute__((ext_vector_type(8))) unsigned short u16x8;
typedef __attribute__((ext_vector_type(4))) float          f4;

__device__ __forceinline__ float bf2f(unsigned short u) {
    union { unsigned int i; float f; } x; x.i = ((unsigned int)u) << 16; return x.f;
}
__device__ __forceinline__ unsigned short f2bf(float f) {
    __hip_bfloat16 h = __float2bfloat16(f);
    return *reinterpret_cast<unsigned short*>(&h);
}
__device__ __forceinline__ void gload_lds16(const void* g, void* l) {
    __builtin_amdgcn_global_load_lds(
        (const __attribute__((address_space(1))) unsigned int*)g,
        (__attribute__((address_space(3))) unsigned int*)l, 16, 0, 0);
}

// Convert the 4 weight matrices (each 512x512 fp32) to bf16, concatenated.
__global__ __launch_bounds__(256) void cvt_w4(const float* __restrict__ a,
                                              const float* __restrict__ b,
                                              const float* __restrict__ c,
                                              const float* __restrict__ d,
                                              unsigned short* __restrict__ o) {
    const int i   = (blockIdx.x * 256 + threadIdx.x) * 8;
    const int seg = i >> 18;
    const int off = i & 262143;
    const float* s = (seg == 0) ? a : (seg == 1) ? b : (seg == 2) ? c : d;
    f4 x0 = *(const f4*)(s + off);
    f4 x1 = *(const f4*)(s + off + 4);
    unsigned short t[8];
    t[0] = f2bf(x0[0]); t[1] = f2bf(x0[1]); t[2] = f2bf(x0[2]); t[3] = f2bf(x0[3]);
    t[4] = f2bf(x1[0]); t[5] = f2bf(x1[1]); t[6] = f2bf(x1[2]); t[7] = f2bf(x1[3]);
    *(u16x8*)(o + i) = *(u16x8*)t;
}

// OUT[m][n] = (sum_k A[m][k] * W[n][k] + bias[n]) * scale
// FULL-N blocks: one block = 64 rows x all 512 cols, so each A panel crosses
// L2 exactly once (kills the 4x A re-read that made prior GEMMs L2-miss-BW
// bound at ~1 TB/s/XCD). Double-buffered dynamic LDS, BK=32, counted vmcnt
// with vmcnt(0) TAIL (round-5 bug), both-sides XOR swizzle (rule #21).
template <bool AF32, bool OF32>
__global__ __launch_bounds__(256, 2) void gemm_fn(const void* __restrict__ Ap,
                                                  const unsigned short* __restrict__ Wb,
                                                  const float* __restrict__ bias,
                                                  void* __restrict__ Outp,
                                                  float scale) {
    constexpr int KD = 512, BK = 32, NT = KD / BK;            // 16 K-tiles
    constexpr int ASZ = AF32 ? 64 * BK * 4 : 64 * BK * 2;     // 8 KB / 4 KB
    constexpr int WSZ = 512 * BK * 2;                          // 32 KB
    constexpr int STRIDE = ASZ + WSZ;
    extern __shared__ unsigned char lds[];                     // 2*STRIDE bytes

    const int tid  = threadIdx.x;
    const int lane = tid & 63;
    const int w    = tid >> 6;            // wave id 0..3 -> cols [w*128, w*128+128)
    const size_t m0 = (size_t)blockIdx.x * 64;

    const float*          Af = (const float*)Ap;
    const unsigned short* Ab = (const unsigned short*)Ap;

    const int fr = lane & 15;             // frag row (A) / col (B/D)
    const int j4 = lane >> 4;             // k-slot 0..3 (k = j4*8 + e)

    f4 acc[4][8];
#pragma unroll
    for (int i = 0; i < 4; ++i)
#pragma unroll
        for (int j = 0; j < 8; ++j) acc[i][j] = (f4)(0.0f);

    auto stage = [&](int t, int buf) {
        const int kt = t * BK;
        unsigned char* base = lds + buf * STRIDE;
        if constexpr (AF32) {
            // A fp32 [64][32]: 8 slots(16B)/row; phys slot p holds logical p^(row&7)
#pragma unroll
            for (int i = 0; i < 2; ++i) {
                const int f = i * 256 + tid;
                const int row = f >> 3, p = f & 7;
                const int s = p ^ (row & 7);
                gload_lds16(Af + (m0 + row) * KD + kt + s * 4, base + f * 16);
            }
        } else {
            // A bf16 [64][32]: 4 slots/row; flat perm f -> f^((f>>3)&7)
            const int f = tid;
            const int l = f ^ ((f >> 3) & 7);
            gload_lds16(Ab + (m0 + (l >> 2)) * KD + kt + (l & 3) * 8, base + f * 16);
        }
        // W bf16 [512][32]: 2048 slots, same flat perm
#pragma unroll
        for (int i = 0; i < 8; ++i) {
            const int f = i * 256 + tid;
            const int l = f ^ ((f >> 3) & 7);
            gload_lds16(Wb + (size_t)(l >> 2) * KD + kt + (l & 3) * 8,
                        base + ASZ + f * 16);
        }
    };

    stage(0, 0);
    stage(1, 1);

    for (int t = 0; t < NT; ++t) {
        const int buf = t & 1;
        unsigned char* base = lds + buf * STRIDE;
        // wait for tile t's own loads; keep tile t+1's in flight (tail: drain all)
        if (t + 1 < NT) {
            if constexpr (AF32) asm volatile("s_waitcnt vmcnt(10)" ::: "memory");
            else                asm volatile("s_waitcnt vmcnt(9)"  ::: "memory");
        } else {
            asm volatile("s_waitcnt vmcnt(0)" ::: "memory");
        }
        __builtin_amdgcn_s_barrier();         // all waves' tile-t loads done
        __builtin_amdgcn_sched_barrier(0);

        s16x8 af[4];
#pragma unroll
        for (int mi = 0; mi < 4; ++mi) {
            const int row = mi * 16 + fr;
            if constexpr (AF32) {
                const int r7 = row & 7;
                const int s0 = j4 * 2;
                f4 x0 = *(const f4*)(base + row * 128 + ((s0 ^ r7) << 4));
                f4 x1 = *(const f4*)(base + row * 128 + (((s0 + 1) ^ r7) << 4));
                unsigned short u[8];
                u[0] = f2bf(x0[0]); u[1] = f2bf(x0[1]); u[2] = f2bf(x0[2]); u[3] = f2bf(x0[3]);
                u[4] = f2bf(x1[0]); u[5] = f2bf(x1[1]); u[6] = f2bf(x1[2]); u[7] = f2bf(x1[3]);
                af[mi] = *(s16x8*)u;
            } else {
                const int L = (row << 2) | j4;
                const int P = L ^ ((L >> 3) & 7);
                af[mi] = *(const s16x8*)(base + (P << 4));
            }
        }
#pragma unroll
        for (int ni = 0; ni < 8; ++ni) {
            const int nrow = w * 128 + ni * 16 + fr;
            const int L = (nrow << 2) | j4;
            const int P = L ^ ((L >> 3) & 7);
            const s16x8 bf = *(const s16x8*)(base + ASZ + (P << 4));
#pragma unroll
            for (int mi = 0; mi < 4; ++mi)
                acc[mi][ni] = __builtin_amdgcn_mfma_f32_16x16x32_bf16(
                    af[mi], bf, acc[mi][ni], 0, 0, 0);
        }

        __builtin_amdgcn_sched_barrier(0);
        __builtin_amdgcn_s_barrier();         // all waves done reading buf
        __builtin_amdgcn_sched_barrier(0);
        if (t + 2 < NT) stage(t + 2, buf);    // refill the buffer just drained
    }

    const int rq = (lane >> 4) << 2;
#pragma unroll
    for (int ni = 0; ni < 8; ++ni) {
        const int   col = w * 128 + ni * 16 + fr;
        const float bv  = bias[col];
#pragma unroll
        for (int mi = 0; mi < 4; ++mi) {
            const size_t rbase = m0 + mi * 16 + rq;
#pragma unroll
            for (int r = 0; r < 4; ++r) {
                const float val = (acc[mi][ni][r] + bv) * scale;
                if constexpr (OF32)
                    ((float*)Outp)[(rbase + r) * KD + col] = val;
                else
                    ((unsigned short*)Outp)[(rbase + r) * KD + col] = f2bf(val);
            }
        }
    }
}

// LDS-tiled NAT: one block per (b, head, 16x16 pixel tile). (unchanged)
__global__ __launch_bounds__(256) void natt(const unsigned short* __restrict__ qh,
                                            const unsigned short* __restrict__ kh,
                                            const unsigned short* __restrict__ vh,
                                            const float* __restrict__ rpb,
                                            unsigned short* __restrict__ xout) {
    constexpr int LDK = 40;
    __shared__ unsigned short KV[484][LDK];
    __shared__ float Rs[169];

    const int tid = threadIdx.x;
    const int h   = blockIdx.z & 15;
    const int b   = blockIdx.z >> 4;
    const int x0  = blockIdx.x * 16;
    const int y0  = blockIdx.y * 16;
    const int ux0 = min(max(x0 - 3, 0), 106);
    const int uy0 = min(max(y0 - 3, 0), 106);
    const int tx  = tid & 15;
    const int ty  = tid >> 4;
    const int x   = x0 + tx;
    const int y   = y0 + ty;

    if (tid < 169) Rs[tid] = rpb[h * 169 + tid];

    const long imgbase = (long)b * 128 * 128;

#pragma unroll 2
    for (int kk = tid; kk < 484; kk += 256) {
        const int ky = uy0 + kk / 22;
        const int kx = ux0 + kk % 22;
        const unsigned short* src = kh + (imgbase + ky * 128 + kx) * 512 + h * 32;
#pragma unroll
        for (int j = 0; j < 4; ++j)
            *(u16x8*)&KV[kk][j * 8] = *(const u16x8*)(src + j * 8);
    }

    const long pix = imgbase + y * 128 + x;
    const unsigned short* qp = qh + pix * 512 + h * 32;
    float qv[32];
#pragma unroll
    for (int j = 0; j < 4; ++j) {
        u16x8 v = *(const u16x8*)(qp + j * 8);
#pragma unroll
        for (int e = 0; e < 8; ++e) qv[j * 8 + e] = bf2f(v[e]);
    }

    const int myy = min(max(y - 3, 0), 121) - uy0;
    const int myx = min(max(x - 3, 0), 121) - ux0;
    const int pbY = (y < 3) ? (6 - y) : ((y >= 125) ? (127 - y) : 3);
    const int pbX = (x < 3) ? (6 - x) : ((x >= 125) ? (127 - x) : 3);

    __syncthreads();

    float logit[49];
#pragma unroll
    for (int a = 0; a < 7; ++a) {
        const int rowk = (myy + a) * 22 + myx;
#pragma unroll
        for (int c = 0; c < 7; ++c) {
            const unsigned short* kp = &KV[rowk + c][0];
            float s = 0.f;
#pragma unroll
            for (int j = 0; j < 4; ++j) {
                u16x8 v = *(const u16x8*)(kp + j * 8);
#pragma unroll
                for (int e = 0; e < 8; ++e) s = fmaf(qv[j * 8 + e], bf2f(v[e]), s);
            }
            logit[a * 7 + c] = s + Rs[(pbY + a) * 13 + pbX + c];
        }
    }

    float m = logit[0];
#pragma unroll
    for (int i = 1; i < 49; ++i) m = fmaxf(m, logit[i]);
    float sum = 0.f;
#pragma unroll
    for (int i = 0; i < 49; ++i) {
        float p = exp2f((logit[i] - m) * 1.4426950408889634f);
        logit[i] = p;
        sum += p;
    }
    const float rinv = 1.f / sum;
#pragma unroll
    for (int i = 0; i < 49; ++i) logit[i] *= rinv;

    __syncthreads();

#pragma unroll 2
    for (int kk = tid; kk < 484; kk += 256) {
        const int ky = uy0 + kk / 22;
        const int kx = ux0 + kk % 22;
        const unsigned short* src = vh + (imgbase + ky * 128 + kx) * 512 + h * 32;
#pragma unroll
        for (int j = 0; j < 4; ++j)
            *(u16x8*)&KV[kk][j * 8] = *(const u16x8*)(src + j * 8);
    }
    __syncthreads();

    float acc[32];
#pragma unroll
    for (int d = 0; d < 32; ++d) acc[d] = 0.f;
#pragma unroll
    for (int a = 0; a < 7; ++a) {
        const int rowk = (myy + a) * 22 + myx;
#pragma unroll
        for (int c = 0; c < 7; ++c) {
            const unsigned short* vp = &KV[rowk + c][0];
            const float wgt = logit[a * 7 + c];
#pragma unroll
            for (int j = 0; j < 4; ++j) {
                u16x8 v = *(const u16x8*)(vp + j * 8);
#pragma unroll
                for (int e = 0; e < 8; ++e)
                    acc[j * 8 + e] = fmaf(wgt, bf2f(v[e]), acc[j * 8 + e]);
            }
        }
    }

    unsigned short* op = xout + pix * 512 + h * 32;
#pragma unroll
    for (int j = 0; j < 4; ++j) {
        unsigned short t[8];
#pragma unroll
        for (int e = 0; e < 8; ++e) t[e] = f2bf(acc[j * 8 + e]);
        *(u16x8*)(op + j * 8) = *(u16x8*)t;
    }
}

extern "C" void kernel_launch(void* const* d_in, const int* in_sizes, int n_in,
                              void* d_out, int out_size, void* d_ws, size_t ws_size,
                              hipStream_t stream) {
    const float* q   = (const float*)d_in[0];
    const float* k   = (const float*)d_in[1];
    const float* v   = (const float*)d_in[2];
    const float* wq  = (const float*)d_in[3];
    const float* bq  = (const float*)d_in[4];
    const float* wk  = (const float*)d_in[5];
    const float* bk  = (const float*)d_in[6];
    const float* wv  = (const float*)d_in[7];
    const float* bv  = (const float*)d_in[8];
    const float* rpb = (const float*)d_in[9];
    const float* wo  = (const float*)d_in[10];
    const float* bo  = (const float*)d_in[11];

    const long P = 2l * 128 * 128;  // 32768 pixels
    unsigned short* qh = (unsigned short*)d_ws;
    unsigned short* kh = qh + P * 512;
    unsigned short* vh = kh + P * 512;
    unsigned short* xb = vh + P * 512;
    unsigned short* Wb = xb + P * 512;   // 4 x 512 x 512 bf16 (2 MB)

    const float scale = 0.17677669529663687f;  // 32^-0.5

    // dynamic LDS: 2*(ASZ+WSZ)
    const size_t smemF = 2 * (64 * 32 * 4 + 512 * 32 * 2);  // 81920
    const size_t smemB = 2 * (64 * 32 * 2 + 512 * 32 * 2);  // 73728

    cvt_w4<<<512, 256, 0, stream>>>(wq, wk, wv, wo, Wb);

    gemm_fn<true, false><<<512, 256, smemF, stream>>>(q, Wb,          bq, qh, scale);
    gemm_fn<true, false><<<512, 256, smemF, stream>>>(k, Wb + 262144, bk, kh, 1.0f);
    gemm_fn<true, false><<<512, 256, smemF, stream>>>(v, Wb + 524288, bv, vh, 1.0f);

    natt<<<dim3(8, 8, 32), 256, 0, stream>>>(qh, kh, vh, rpb, xb);

    gemm_fn<false, true><<<512, 256, smemB, stream>>>(xb, Wb + 786432, bo, (float*)d_out, 1.0f);
}